// Round 1
// baseline (272.334 us; speedup 1.0000x reference)
//
#include <hip/hip_runtime.h>

// Volume rendering: one thread per ray, sequential transmittance scan over
// 128 samples, float4-vectorized loads. Memory-bound; ~203 MB total traffic.

#define N_SAMPLES 128
#define NCHUNK (N_SAMPLES / 4)

__global__ __launch_bounds__(256) void volrend_kernel(
    const float* __restrict__ rgb,      // (n_rays, 128, 3)
    const float* __restrict__ density,  // (n_rays, 128, 1)
    const float* __restrict__ z_vals,   // (n_rays, 128)
    const float* __restrict__ rays_d,   // (n_rays, 3)
    float* __restrict__ out_rgb,        // (n_rays, 3)
    float* __restrict__ out_depth,      // (n_rays,)
    float* __restrict__ out_w,          // (n_rays, 128)
    int n_rays)
{
    int ray = blockIdx.x * blockDim.x + threadIdx.x;
    if (ray >= n_rays) return;

    const float4* z4 = (const float4*)(z_vals + (size_t)ray * N_SAMPLES);
    const float4* d4 = (const float4*)(density + (size_t)ray * N_SAMPLES);
    const float4* r4 = (const float4*)(rgb + (size_t)ray * N_SAMPLES * 3);
    float4* w4 = (float4*)(out_w + (size_t)ray * N_SAMPLES);

    float dxv = rays_d[ray * 3 + 0];
    float dyv = rays_d[ray * 3 + 1];
    float dzv = rays_d[ray * 3 + 2];
    float norm = sqrtf(dxv * dxv + dyv * dyv + dzv * dzv);

    float T = 1.0f;
    float cr = 0.0f, cg = 0.0f, cb = 0.0f, cd = 0.0f;

    float4 zc = z4[0];
    for (int c = 0; c < NCHUNK; ++c) {
        float4 zn;
        if (c < NCHUNK - 1) {
            zn = z4[c + 1];
        } else {
            zn = make_float4(0.0f, 0.0f, 0.0f, 0.0f);
        }
        float4 dd = d4[c];
        float4 r0 = r4[3 * c + 0];
        float4 r1 = r4[3 * c + 1];
        float4 r2 = r4[3 * c + 2];

        float zs[5]  = {zc.x, zc.y, zc.z, zc.w, zn.x};
        float den[4] = {dd.x, dd.y, dd.z, dd.w};
        float rr[12] = {r0.x, r0.y, r0.z, r0.w,
                        r1.x, r1.y, r1.z, r1.w,
                        r2.x, r2.y, r2.z, r2.w};
        float w[4];

        #pragma unroll
        for (int j = 0; j < 4; ++j) {
            bool last = (c == NCHUNK - 1) && (j == 3);
            float dist = last ? 1e10f : (zs[j + 1] - zs[j]);
            float a = 1.0f - expf(-fmaxf(den[j], 0.0f) * dist * norm);
            float wi = a * T;
            T = T * (1.0f - a + 1e-10f);
            w[j] = wi;
            cr += wi * rr[3 * j + 0];
            cg += wi * rr[3 * j + 1];
            cb += wi * rr[3 * j + 2];
            cd += wi * zs[j];
        }

        w4[c] = make_float4(w[0], w[1], w[2], w[3]);
        zc = zn;
    }

    out_rgb[ray * 3 + 0] = cr;
    out_rgb[ray * 3 + 1] = cg;
    out_rgb[ray * 3 + 2] = cb;
    out_depth[ray] = cd;
}

extern "C" void kernel_launch(void* const* d_in, const int* in_sizes, int n_in,
                              void* d_out, int out_size, void* d_ws, size_t ws_size,
                              hipStream_t stream) {
    const float* rgb     = (const float*)d_in[0];
    const float* density = (const float*)d_in[1];
    const float* z_vals  = (const float*)d_in[2];
    const float* rays_d  = (const float*)d_in[3];

    int n_rays = in_sizes[3] / 3;   // rays_d is (n_rays, 3)

    float* out       = (float*)d_out;
    float* out_rgb   = out;                          // n_rays*3
    float* out_depth = out + (size_t)n_rays * 3;     // n_rays
    float* out_w     = out_depth + n_rays;           // n_rays*128

    int block = 256;
    int grid = (n_rays + block - 1) / block;
    volrend_kernel<<<grid, block, 0, stream>>>(rgb, density, z_vals, rays_d,
                                               out_rgb, out_depth, out_w, n_rays);
}

// Round 2
// 203.173 us; speedup vs baseline: 1.3404x; 1.3404x over previous
//
#include <hip/hip_runtime.h>

// Volume rendering: one WAVE (64 lanes) per ray, 2 samples per lane.
// Coalesced float2 loads/stores; exclusive cumprod via wave prefix-product
// (shfl_up); weighted sums via shfl_xor butterfly reduce. No LDS.

#define N_SAMPLES 128

__global__ __launch_bounds__(256) void volrend_kernel(
    const float* __restrict__ rgb,      // (n_rays, 128, 3)
    const float* __restrict__ density,  // (n_rays, 128, 1)
    const float* __restrict__ z_vals,   // (n_rays, 128)
    const float* __restrict__ rays_d,   // (n_rays, 3)
    float* __restrict__ out_rgb,        // (n_rays, 3)
    float* __restrict__ out_depth,      // (n_rays,)
    float* __restrict__ out_w,          // (n_rays, 128)
    int n_rays)
{
    int tid  = blockIdx.x * blockDim.x + threadIdx.x;
    int ray  = tid >> 6;          // one wave per ray
    int lane = threadIdx.x & 63;
    if (ray >= n_rays) return;

    // ---- coalesced loads: lane i handles samples 2i and 2i+1 ----
    const float2* z2 = (const float2*)(z_vals  + (size_t)ray * N_SAMPLES);
    const float2* d2 = (const float2*)(density + (size_t)ray * N_SAMPLES);
    const float2* r2 = (const float2*)(rgb     + (size_t)ray * N_SAMPLES * 3);

    float2 z   = z2[lane];
    float2 den = d2[lane];
    float2 ra  = r2[3 * lane + 0];   // s0.r, s0.g
    float2 rb  = r2[3 * lane + 1];   // s0.b, s1.r
    float2 rc  = r2[3 * lane + 2];   // s1.g, s1.b

    // ray direction norm (wave-uniform address -> scalar load)
    float dx = rays_d[ray * 3 + 0];
    float dy = rays_d[ray * 3 + 1];
    float dz = rays_d[ray * 3 + 2];
    float nrm = sqrtf(dx * dx + dy * dy + dz * dz);

    // ---- dists ----
    float znext = __shfl_down(z.x, 1);           // z[2i+2] from lane i+1
    float dist0 = (z.y - z.x) * nrm;
    float dist1 = (lane == 63) ? (1e10f * nrm) : ((znext - z.y) * nrm);

    // ---- alpha ----
    float a0 = 1.0f - __expf(-fmaxf(den.x, 0.0f) * dist0);
    float a1 = 1.0f - __expf(-fmaxf(den.y, 0.0f) * dist1);
    float p0 = 1.0f - a0 + 1e-10f;
    float p1 = 1.0f - a1 + 1e-10f;

    // ---- wave-level exclusive prefix product of p over 128 samples ----
    float pp   = p0 * p1;          // per-lane pair product
    float incl = pp;
    #pragma unroll
    for (int off = 1; off < 64; off <<= 1) {
        float v = __shfl_up(incl, off);
        if (lane >= off) incl *= v;
    }
    float ex = __shfl_up(incl, 1);
    if (lane == 0) ex = 1.0f;      // T for sample 2i
    // T for sample 2i+1 = ex * p0

    float w0 = a0 * ex;
    float w1 = a1 * (ex * p0);

    // ---- coalesced weights store ----
    ((float2*)(out_w + (size_t)ray * N_SAMPLES))[lane] = make_float2(w0, w1);

    // ---- weighted sums ----
    float cr = w0 * ra.x + w1 * rb.y;
    float cg = w0 * ra.y + w1 * rc.x;
    float cb = w0 * rb.x + w1 * rc.y;
    float cd = w0 * z.x  + w1 * z.y;

    #pragma unroll
    for (int off = 32; off >= 1; off >>= 1) {
        cr += __shfl_xor(cr, off);
        cg += __shfl_xor(cg, off);
        cb += __shfl_xor(cb, off);
        cd += __shfl_xor(cd, off);
    }

    if (lane == 0) {
        out_rgb[ray * 3 + 0] = cr;
        out_rgb[ray * 3 + 1] = cg;
        out_rgb[ray * 3 + 2] = cb;
        out_depth[ray] = cd;
    }
}

extern "C" void kernel_launch(void* const* d_in, const int* in_sizes, int n_in,
                              void* d_out, int out_size, void* d_ws, size_t ws_size,
                              hipStream_t stream) {
    const float* rgb     = (const float*)d_in[0];
    const float* density = (const float*)d_in[1];
    const float* z_vals  = (const float*)d_in[2];
    const float* rays_d  = (const float*)d_in[3];

    int n_rays = in_sizes[3] / 3;   // rays_d is (n_rays, 3)

    float* out       = (float*)d_out;
    float* out_rgb   = out;                          // n_rays*3
    float* out_depth = out + (size_t)n_rays * 3;     // n_rays
    float* out_w     = out_depth + n_rays;           // n_rays*128

    int block = 256;                 // 4 waves = 4 rays per block
    int rays_per_block = block / 64;
    int grid = (n_rays + rays_per_block - 1) / rays_per_block;
    volrend_kernel<<<grid, block, 0, stream>>>(rgb, density, z_vals, rays_d,
                                               out_rgb, out_depth, out_w, n_rays);
}